// Round 15
// baseline (56.515 us; speedup 1.0000x reference)
//
#include <hip/hip_runtime.h>
#include <hip/hip_bf16.h>

typedef __attribute__((ext_vector_type(8)))  short short8;
typedef __attribute__((ext_vector_type(4)))  float f32x4;
typedef __attribute__((ext_vector_type(16))) float f32x16;

#define CIN   16
#define HH    256
#define WW    256
#define OHH   254
#define OWW   254

// LDS patch: [2 cihalf][34 h][36 w][8 ci] bf16, 16B cells (R7/R13-proven:
// px stride 16B -> conflict-free b128 reads). ci-half stride padded +16B.
#define HSTR   (36 * 8)              // 288 ushorts per h row
#define HALF   (34 * HSTR + 8)       // 9800 ushorts per ci-half

__device__ __forceinline__ ushort f2bf(float f) {
    unsigned u = __builtin_bit_cast(unsigned, f);
    unsigned r = (u + 0x7fffu + ((u >> 16) & 1u)) >> 16;
    return (ushort)r;
}

// fast tanh(tanh(x)): exp2-based (verified absmax 3.9e-3 in R1-R14)
__device__ __forceinline__ float dtanh2(float x) {
    const float K = 2.8853900817779268f;   // 2*log2(e)
    float xc = fminf(fmaxf(x, -9.0f), 9.0f);
    float e1 = __builtin_amdgcn_exp2f(K * xc);
    float t1 = 1.0f - 2.0f * __builtin_amdgcn_rcpf(e1 + 1.0f);
    float e2 = __builtin_amdgcn_exp2f(K * t1);
    return 1.0f - 2.0f * __builtin_amdgcn_rcpf(e2 + 1.0f);
}

// Weights fp32 OIHW [64][16][3][3] -> 32x32x16 A-fragments (R9-proven):
// wfrag[tap][j][lane][r]: channel row = j*32+(lane&31), ci = 8*(lane>>5)+r.
__global__ void prep_weights(const float* __restrict__ wsrc, ushort* __restrict__ wfrag) {
    int idx = blockIdx.x * 256 + threadIdx.x;
    if (idx >= 9216) return;
    int r    = idx & 7;
    int lane = (idx >> 3) & 63;
    int j    = (idx >> 9) & 1;
    int tap  = idx >> 10;                 // 0..8
    int ci   = 8 * (lane >> 5) + r;
    int co   = j * 32 + (lane & 31);
    int kh   = tap / 3, kw = tap - 3 * kh;
    wfrag[idx] = f2bf(wsrc[(co * CIN + ci) * 9 + kh * 3 + kw]);
}

// j-split + chunk pipeline + sliding-window B-frags (3 ds_reads/row, not 9).
// Live set ~142 regs at (256,3)=170 cap. R2/R6/R10: never cap below it.
__global__ __launch_bounds__(256, 3) void conv_min_tanh(
        const float* __restrict__ x, const ushort* __restrict__ wfrag,
        const float* __restrict__ bias, float* __restrict__ out) {
    __shared__ ushort lds[2 * HALF];         // 39,200 B patch
    __shared__ ushort mp[2][32][32];         // 4,096 B per-j min planes

    const int tid = threadIdx.x;
    const int n   = blockIdx.z;
    const int oh0 = blockIdx.y * 32;
    const int ow0 = blockIdx.x * 32;
    const int HW  = HH * WW;
    const float* xb = x + (size_t)n * CIN * HW;

    // ---- prologue: stage patch rows 0..15 inline (576 positions) ----
    auto stage0 = [&](int pos) {             // pos = hp*36 + ciq*9 + w4
        int hp  = pos / 36;
        int r2  = pos - hp * 36;
        int ciq = r2 / 9;
        int w4  = r2 - ciq * 9;
        int hg  = min(oh0 + hp, HH - 1);
        int wg  = min(ow0 + 4 * w4, WW - 4);
        const float* src = xb + (size_t)(ciq * 4) * HW + hg * WW + wg;
        f32x4 v0 = *reinterpret_cast<const f32x4*>(src);
        f32x4 v1 = *reinterpret_cast<const f32x4*>(src + HW);
        f32x4 v2 = *reinterpret_cast<const f32x4*>(src + 2 * HW);
        f32x4 v3 = *reinterpret_cast<const f32x4*>(src + 3 * HW);
        ushort* dst = &lds[(ciq >> 1) * HALF + (hp * 36 + 4 * w4) * 8 + (ciq & 1) * 4];
#pragma unroll
        for (int e = 0; e < 4; ++e) {
            unsigned lo, hi;
            asm("v_cvt_pk_bf16_f32 %0, %1, %2" : "=v"(lo) : "v"(v0[e]), "v"(v1[e]));
            asm("v_cvt_pk_bf16_f32 %0, %1, %2" : "=v"(hi) : "v"(v2[e]), "v"(v3[e]));
            uint2 pk; pk.x = lo; pk.y = hi;
            *reinterpret_cast<uint2*>(dst + e * 8) = pk;
        }
    };
    stage0(tid);
    stage0(tid + 256);
    if (tid < 64) stage0(tid + 512);

    // ---- stage-chunk constants: 6 rows x 36 = 216 positions, 1 per thread ----
    const bool sa   = (tid < 216);
    const int lr0   = tid / 36;                          // 0..5
    const int rm0   = tid - lr0 * 36;
    const int ciq0  = rm0 / 9;
    const int w40   = rm0 - ciq0 * 9;
    const int wg0   = min(ow0 + 4 * w40, WW - 4);
    const int gc0   = ciq0 * 4 * HW + wg0;               // plane+col (dwords)
    const int ld0   = (ciq0 >> 1) * HALF + (4 * w40) * 8 + (ciq0 & 1) * 4;

    const int lane  = tid & 63;
    const int wid   = tid >> 6;
    const int jw    = wid & 1;           // channel tile (32 channels)
    const int rq    = wid >> 1;          // row quad: rows rq*4..rq*4+3 of each chunk
    const int px    = lane & 31;
    const int khalf = lane >> 5;

    // ---- weight tile (A-operand), bias ----
    short8 wf[9];
#pragma unroll
    for (int tap = 0; tap < 9; ++tap)
        wf[tap] = *reinterpret_cast<const short8*>(wfrag + ((tap * 2 + jw) * 64 + lane) * 8);
    f32x16 bi;                           // D row = (r&3)+8*(r>>2)+4*khalf
#pragma unroll
    for (int q4 = 0; q4 < 4; ++q4) {
        f32x4 b = *reinterpret_cast<const f32x4*>(bias + jw * 32 + 4 * khalf + 8 * q4);
#pragma unroll
        for (int s = 0; s < 4; ++s) bi[q4 * 4 + s] = b[s];
    }
    const ushort* bptr = &lds[khalf * HALF + (rq * 4) * HSTR + px * 8];

    __syncthreads();                     // rows 0..15 ready

    f32x4 ra0, ra1, ra2, ra3;            // in-flight stage chunk (16 regs)

    // ---- chunk loop: issue stage(q+1) -> compute(q) -> drain+write -> barrier ----
#pragma unroll
    for (int q = 0; q < 4; ++q) {
        if (q < 3 && sa) {               // stage chunk q+1: patch rows 16+6q .. 21+6q
            int hg = min(oh0 + 16 + 6 * q + lr0, HH - 1);
            const float* s = xb + gc0 + hg * WW;
            asm volatile("global_load_dwordx4 %0, %1, off" : "=v"(ra0) : "v"(s) : "memory");
            asm volatile("global_load_dwordx4 %0, %1, off" : "=v"(ra1) : "v"(s + HW) : "memory");
            asm volatile("global_load_dwordx4 %0, %1, off" : "=v"(ra2) : "v"(s + 2 * HW) : "memory");
            asm volatile("global_load_dwordx4 %0, %1, off" : "=v"(ra3) : "v"(s + 3 * HW) : "memory");
        }

        // ---- compute chunk q (rows 8q+rq*4 .. +3), sliding 3-row window ----
        {
            const int base = 8 * q;      // + rq*4 folded into bptr
            short8 w0[3], w1[3];
#pragma unroll
            for (int kw = 0; kw < 3; ++kw) {
                w0[kw] = *reinterpret_cast<const short8*>(bptr + (base + 0) * HSTR + kw * 8);
                w1[kw] = *reinterpret_cast<const short8*>(bptr + (base + 1) * HSTR + kw * 8);
            }
#pragma unroll
            for (int i = 0; i < 4; ++i) {
                short8 fr[3];
#pragma unroll
                for (int kw = 0; kw < 3; ++kw)
                    fr[kw] = *reinterpret_cast<const short8*>(bptr + (base + i + 2) * HSTR + kw * 8);
                f32x16 a = bi;
#pragma unroll
                for (int kw = 0; kw < 3; ++kw)
                    a = __builtin_amdgcn_mfma_f32_32x32x16_bf16(wf[kw], w0[kw], a, 0, 0, 0);
#pragma unroll
                for (int kw = 0; kw < 3; ++kw)
                    a = __builtin_amdgcn_mfma_f32_32x32x16_bf16(wf[3 + kw], w1[kw], a, 0, 0, 0);
#pragma unroll
                for (int kw = 0; kw < 3; ++kw)
                    a = __builtin_amdgcn_mfma_f32_32x32x16_bf16(wf[6 + kw], fr[kw], a, 0, 0, 0);
                float v = a[0];
#pragma unroll
                for (int r = 1; r < 16; ++r) v = fminf(v, a[r]);
                v = fminf(v, __shfl_xor(v, 32, 64));
                if (lane < 32) mp[jw][8 * q + rq * 4 + i][px] = f2bf(v);
#pragma unroll
                for (int kw = 0; kw < 3; ++kw) { w0[kw] = w1[kw]; w1[kw] = fr[kw]; }
            }
        }

        if (q < 3) {                     // drain the single outstanding chunk, write it
            asm volatile("s_waitcnt vmcnt(0)" ::: "memory");
            if (sa) {
                ushort* dst = &lds[ld0 + ((16 + 6 * q + lr0) * 36) * 8];
#pragma unroll
                for (int e = 0; e < 4; ++e) {
                    unsigned lo, hi;
                    asm("v_cvt_pk_bf16_f32 %0, %1, %2" : "=v"(lo) : "v"(ra0[e]), "v"(ra1[e]));
                    asm("v_cvt_pk_bf16_f32 %0, %1, %2" : "=v"(hi) : "v"(ra2[e]), "v"(ra3[e]));
                    uint2 pk; pk.x = lo; pk.y = hi;
                    *reinterpret_cast<uint2*>(dst + e * 8) = pk;
                }
            }
            __syncthreads();
        }
    }

    __syncthreads();                     // mp planes visible

    // ---- final: 4 px per thread: min(j0,j1), double-tanh, float4 store ----
    const int row = tid >> 3, px4 = (tid & 7) * 4;
    uint2 p0 = *reinterpret_cast<const uint2*>(&mp[0][row][px4]);
    uint2 p1 = *reinterpret_cast<const uint2*>(&mp[1][row][px4]);
    f32x4 y;
#pragma unroll
    for (int e = 0; e < 4; ++e) {
        unsigned w0 = (e < 2) ? p0.x : p0.y;
        unsigned w1 = (e < 2) ? p1.x : p1.y;
        float f0 = __builtin_bit_cast(float, (e & 1) ? (w0 & 0xffff0000u) : (w0 << 16));
        float f1 = __builtin_bit_cast(float, (e & 1) ? (w1 & 0xffff0000u) : (w1 << 16));
        y[e] = dtanh2(fminf(f0, f1));
    }
    const int oh = oh0 + row, ow = ow0 + px4;
    if (oh < OHH) {
        float* op = &out[((size_t)n * OHH + oh) * OWW + ow];
        if (ow + 3 < OWW) {
            *reinterpret_cast<f32x4*>(op) = y;
        } else {
#pragma unroll
            for (int e = 0; e < 4; ++e)
                if (ow + e < OWW) op[e] = y[e];
        }
    }
}

extern "C" void kernel_launch(void* const* d_in, const int* in_sizes, int n_in,
                              void* d_out, int out_size, void* d_ws, size_t ws_size,
                              hipStream_t stream) {
    const float* x = (const float*)d_in[0];
    const float* w = (const float*)d_in[1];
    const float* b = (const float*)d_in[2];
    float* out     = (float*)d_out;
    ushort* wfrag  = (ushort*)d_ws;          // 18 KiB

    prep_weights<<<36, 256, 0, stream>>>(w, wfrag);
    dim3 grid(8, 8, 32);                     // (owT, ohT, n), 32x32 tiles
    conv_min_tanh<<<grid, dim3(256, 1, 1), 0, stream>>>(x, wfrag, b, out);
}

// Round 16
// 51.853 us; speedup vs baseline: 1.0899x; 1.0899x over previous
//
#include <hip/hip_runtime.h>
#include <hip/hip_bf16.h>

typedef __attribute__((ext_vector_type(8)))  short short8;
typedef __attribute__((ext_vector_type(4)))  float f32x4;
typedef __attribute__((ext_vector_type(16))) float f32x16;

#define CIN   16
#define HH    256
#define WW    256
#define OHH   254
#define OWW   254
#define HW    (HH * WW)

// LDS row-ring: [2 cihalf][16 slot][36 w][8 ci] bf16, 16B cells (R7/R13-proven
// geometry: px stride 16B -> conflict-free b128). Half stride padded +16B.
#define SLOTU  (36 * 8)              // 288 ushorts per patch row
#define HALF_R (16 * SLOTU + 8)      // 4616 ushorts per ci-half
// ring = 18,464 B; + mp 1 KB -> ~19.5 KB LDS

__device__ __forceinline__ ushort f2bf(float f) {
    unsigned u = __builtin_bit_cast(unsigned, f);
    unsigned r = (u + 0x7fffu + ((u >> 16) & 1u)) >> 16;
    return (ushort)r;
}

// fast tanh(tanh(x)): exp2-based (verified absmax 3.9e-3 in R1-R15)
__device__ __forceinline__ float dtanh2(float x) {
    const float K = 2.8853900817779268f;   // 2*log2(e)
    float xc = fminf(fmaxf(x, -9.0f), 9.0f);
    float e1 = __builtin_amdgcn_exp2f(K * xc);
    float t1 = 1.0f - 2.0f * __builtin_amdgcn_rcpf(e1 + 1.0f);
    float e2 = __builtin_amdgcn_exp2f(K * t1);
    return 1.0f - 2.0f * __builtin_amdgcn_rcpf(e2 + 1.0f);
}

// Weights fp32 OIHW [64][16][3][3] -> 32x32x16 A-fragments (R9-proven):
// wfrag[tap][j][lane][r]: channel row = j*32+(lane&31), ci = 8*(lane>>5)+r.
__global__ void prep_weights(const float* __restrict__ wsrc, ushort* __restrict__ wfrag) {
    int idx = blockIdx.x * 256 + threadIdx.x;
    if (idx >= 9216) return;
    int r    = idx & 7;
    int lane = (idx >> 3) & 63;
    int j    = (idx >> 9) & 1;
    int tap  = idx >> 10;                 // 0..8
    int ci   = 8 * (lane >> 5) + r;
    int co   = j * 32 + (lane & 31);
    int kh   = tap / 3, kw = tap - 3 * kh;
    wfrag[idx] = f2bf(wsrc[(co * CIN + ci) * 9 + kh * 3 + kw]);
}

// Persistent half-strip kernel: 32 cols x 128 rows per block, 16-slot ring,
// 2-deep chunk prefetch with counted vmcnt(4) + RAW s_barrier (no vmcnt drain:
// __syncthreads emits vmcnt(0) before s_barrier -- that killed R14's pipeline).
__global__ __launch_bounds__(256, 2) void conv_min_tanh(
        const float* __restrict__ x, const ushort* __restrict__ wfrag,
        const float* __restrict__ bias, float* __restrict__ out) {
    __shared__ ushort ring[2 * HALF_R];      // 18,464 B
    __shared__ ushort mp[2][2][4][32];       // 1,024 B (parity-double-buffered)

    const int tid   = threadIdx.x;
    const int ow0   = blockIdx.x * 32;
    const int hbase = blockIdx.y * 128;      // half-strip base row
    const int n     = blockIdx.z;
    const float* xb = x + (size_t)n * CIN * HW;

    // ---- prologue: stage patch rows hbase..hbase+7 (chunks 0,1) inline ----
    auto stage_inline = [&](int pos) {       // pos = lr*36 + ciq*9 + w4, lr 0..7
        int lr  = pos / 36;
        int rm  = pos - lr * 36;
        int ciq = rm / 9;
        int w4  = rm - ciq * 9;
        int hg  = min(hbase + lr, HH - 1);
        int wg  = min(ow0 + 4 * w4, WW - 4);
        const float* src = xb + (size_t)(ciq * 4) * HW + hg * WW + wg;
        f32x4 v0 = *reinterpret_cast<const f32x4*>(src);
        f32x4 v1 = *reinterpret_cast<const f32x4*>(src + HW);
        f32x4 v2 = *reinterpret_cast<const f32x4*>(src + 2 * HW);
        f32x4 v3 = *reinterpret_cast<const f32x4*>(src + 3 * HW);
        ushort* dst = &ring[(ciq >> 1) * HALF_R + lr * SLOTU + (4 * w4) * 8 + (ciq & 1) * 4];
#pragma unroll
        for (int e = 0; e < 4; ++e) {
            unsigned lo, hi;
            asm("v_cvt_pk_bf16_f32 %0, %1, %2" : "=v"(lo) : "v"(v0[e]), "v"(v1[e]));
            asm("v_cvt_pk_bf16_f32 %0, %1, %2" : "=v"(hi) : "v"(v2[e]), "v"(v3[e]));
            uint2 pk; pk.x = lo; pk.y = hi;
            *reinterpret_cast<uint2*>(dst + e * 8) = pk;
        }
    };
    stage_inline(tid);
    if (tid < 32) stage_inline(tid + 256);   // 288 positions = 8 rows

    // ---- steady-state stage constants (threads 0..143, 1 position each) ----
    const bool sa = (tid < 144);
    const int lr  = tid / 36;                // 0..3 within chunk
    const int rm  = tid - lr * 36;
    const int ciq = rm / 9;
    const int w4  = rm - ciq * 9;
    const int wg  = min(ow0 + 4 * w4, WW - 4);
    const float* gbase = xb + (size_t)(ciq * 4) * HW + wg;
    ushort* sdst = &ring[(ciq >> 1) * HALF_R + (4 * w4) * 8 + (ciq & 1) * 4];

    f32x4 ra0 = {}, ra1 = {}, ra2 = {}, ra3 = {};
    f32x4 rb0 = {}, rb1 = {}, rb2 = {}, rb3 = {};

#define ISSUE(cc, r0, r1, r2, r3)                                              \
    if (sa) {                                                                  \
        int hg = min(hbase + 4 * (cc) + lr, HH - 1);                           \
        const float* s_ = gbase + hg * WW;                                     \
        asm volatile("global_load_dwordx4 %0, %1, off" : "=v"(r0) : "v"(s_) : "memory");           \
        asm volatile("global_load_dwordx4 %0, %1, off" : "=v"(r1) : "v"(s_ + HW) : "memory");      \
        asm volatile("global_load_dwordx4 %0, %1, off" : "=v"(r2) : "v"(s_ + 2 * HW) : "memory");  \
        asm volatile("global_load_dwordx4 %0, %1, off" : "=v"(r3) : "v"(s_ + 3 * HW) : "memory");  \
    }

#define WRITEBK(cc, r0, r1, r2, r3)                                            \
    if (sa) {                                                                  \
        ushort* d_ = sdst + ((4 * (cc) + lr) & 15) * SLOTU;                    \
        _Pragma("unroll")                                                      \
        for (int e = 0; e < 4; ++e) {                                          \
            unsigned lo_, hi_;                                                 \
            asm("v_cvt_pk_bf16_f32 %0, %1, %2" : "=v"(lo_) : "v"(r0[e]), "v"(r1[e]));  \
            asm("v_cvt_pk_bf16_f32 %0, %1, %2" : "=v"(hi_) : "v"(r2[e]), "v"(r3[e]));  \
            uint2 pk_; pk_.x = lo_; pk_.y = hi_;                               \
            *reinterpret_cast<uint2*>(d_ + e * 8) = pk_;                       \
        }                                                                      \
    }

    ISSUE(2, ra0, ra1, ra2, ra3);            // 2-deep prefetch, 8 loads in flight
    ISSUE(3, rb0, rb1, rb2, rb3);

    // ---- weights (A-operand) + bias while loads fly ----
    const int lane  = tid & 63;
    const int wid   = tid >> 6;
    const int jw    = wid & 1;               // channel tile
    const int rq    = wid >> 1;              // row pair within chunk
    const int px    = lane & 31;
    const int khalf = lane >> 5;
    short8 wf[9];
#pragma unroll
    for (int tap = 0; tap < 9; ++tap)
        wf[tap] = *reinterpret_cast<const short8*>(wfrag + ((tap * 2 + jw) * 64 + lane) * 8);
    f32x16 bi;                               // D row = (r&3)+8*(r>>2)+4*khalf
#pragma unroll
    for (int q4 = 0; q4 < 4; ++q4) {
        f32x4 b = *reinterpret_cast<const f32x4*>(bias + jw * 32 + 4 * khalf + 8 * q4);
#pragma unroll
        for (int s = 0; s < 4; ++s) bi[q4 * 4 + s] = b[s];
    }
    const ushort* bptr = &ring[khalf * HALF_R + px * 8];

    asm volatile("s_waitcnt lgkmcnt(0)" ::: "memory");
    __builtin_amdgcn_s_barrier();            // rows 0..7 ready; loads stay in flight

    // ---- 32 chunks: compute(c) | vmcnt(4) write(c+2) issue(c+4) | barrier | out(c) ----
#pragma unroll 2
    for (int c = 0; c < 32; ++c) {
        // compute chunk c: out rows hbase + 4c + 2rq + jj
#pragma unroll
        for (int jj = 0; jj < 2; ++jj) {
            const int R = 4 * c + 2 * rq + jj;
            f32x16 a = bi;
#pragma unroll
            for (int kh = 0; kh < 3; ++kh) {
                const ushort* rp = bptr + ((R + kh) & 15) * SLOTU;
#pragma unroll
                for (int kw = 0; kw < 3; ++kw) {
                    short8 b = *reinterpret_cast<const short8*>(rp + kw * 8);
                    a = __builtin_amdgcn_mfma_f32_32x32x16_bf16(wf[kh * 3 + kw], b, a, 0, 0, 0);
                }
            }
            float v = a[0];
#pragma unroll
            for (int r = 1; r < 16; ++r) v = fminf(v, a[r]);
            v = fminf(v, __shfl_xor(v, 32, 64));
            if (lane < 32) mp[c & 1][jw][2 * rq + jj][px] = f2bf(v);
        }

        // drain ONLY the oldest chunk (counted vmcnt), write it, reissue
        if (c < 31) {
            if ((c & 1) == 0) {
                asm volatile("s_waitcnt vmcnt(4)"
                             : "+v"(ra0), "+v"(ra1), "+v"(ra2), "+v"(ra3) :: "memory");
                WRITEBK(c + 2, ra0, ra1, ra2, ra3);
                ISSUE(min(c + 4, 32), ra0, ra1, ra2, ra3);
            } else {
                asm volatile("s_waitcnt vmcnt(4)"
                             : "+v"(rb0), "+v"(rb1), "+v"(rb2), "+v"(rb3) :: "memory");
                WRITEBK(c + 2, rb0, rb1, rb2, rb3);
                ISSUE(min(c + 4, 32), rb0, rb1, rb2, rb3);
            }
        }

        asm volatile("s_waitcnt lgkmcnt(0)" ::: "memory");
        __builtin_amdgcn_s_barrier();        // NO vmcnt drain: pipeline survives

        // out(c): threads 0..127, one pixel each; mp parity c&1
        if (tid < 128) {
            const int r4 = tid >> 5, opx = tid & 31;
            float f0 = __builtin_bit_cast(float, (unsigned)mp[c & 1][0][r4][opx] << 16);
            float f1 = __builtin_bit_cast(float, (unsigned)mp[c & 1][1][r4][opx] << 16);
            float y  = dtanh2(fminf(f0, f1));
            const int oh = hbase + 4 * c + r4;
            const int ow = ow0 + opx;
            if (oh < OHH && ow < OWW)
                out[((size_t)n * OHH + oh) * OWW + ow] = y;
        }
    }
#undef ISSUE
#undef WRITEBK
}

extern "C" void kernel_launch(void* const* d_in, const int* in_sizes, int n_in,
                              void* d_out, int out_size, void* d_ws, size_t ws_size,
                              hipStream_t stream) {
    const float* x = (const float*)d_in[0];
    const float* w = (const float*)d_in[1];
    const float* b = (const float*)d_in[2];
    float* out     = (float*)d_out;
    ushort* wfrag  = (ushort*)d_ws;          // 18 KiB

    prep_weights<<<36, 256, 0, stream>>>(w, wfrag);
    dim3 grid(8, 2, 32);                     // (w-strip, h-half, n): 512 blocks, 2/CU
    conv_min_tanh<<<grid, dim3(256, 1, 1), 0, stream>>>(x, wfrag, b, out);
}